// Round 1
// 316.685 us; speedup vs baseline: 1.0056x; 1.0056x over previous
//
#include <hip/hip_runtime.h>

// OccupancyConnectivity on a 385^3 fp32 grid (z innermost, y stride 385,
// x stride 148225). total = sum over 3 forward axes of |a[p+off]-a[p]|.
//
// v2 design: de-phased (misaligned dwordx4) global loads so LDS rows are
// globally z-indexed. Each thread computes the 4x4 (rows x z) elements it
// loaded: z-diffs in-register (+shfl for chunk boundary), x-diffs vs
// registers carried from the previous plane (|m-p|), y-diffs via ONE
// aligned ds_read_b128 per row. LDS pipe ~3x lighter than v1; single
// barrier per round (compute reads only the other dbuf half).
// XC=16 (24 x-pairs/chunk) cuts plane redundancy 448->400; 576 blocks are
// all co-resident (4/CU by LDS) so halo lines dedupe in L3.

constexpr int G     = 385;
constexpr int PLANE = G * G;             // 148225

#define TPB   256
#define ZT    3                          // z-tiles of 128 (z in [0,384))
#define YT    12                         // y-tiles of 32 (y in [0,384))
#define XC    16                         // x-chunks of 24 pairs (25 planes)
#define XP    24                         // x-pairs per chunk
#define NBLK  (ZT * YT * XC)             // 576 blocks
#define S     140                        // LDS row stride in floats (mult of 4)

typedef float f4v __attribute__((ext_vector_type(4)));

// misaligned-capable 16B load (address is only 4B-aligned: phase = (x+r)&3)
static __device__ __forceinline__ f4v ldg4u(const float* __restrict__ p) {
    f4v r;
    __builtin_memcpy(&r, p, sizeof(r));
    return r;
}

__global__ __launch_bounds__(TPB) void occ_conn_main(
    const float* __restrict__ a, float* __restrict__ ws)
{
    __shared__ float T[2][33][S];          // 2 x 33 x 140 x 4B = 36960 B
    float s = 0.f;

    const int tz = threadIdx.x & 31;       // z-chunk lane: z = gz0 + 4*tz..+3
    const int ty = threadIdx.x >> 5;       // row group 0..7 (rows ty+8*rr)

    int t = blockIdx.x;
    const int bc = t % XC;  t /= XC;
    const int by = t % YT;  t /= YT;
    const int bz = t;                      // 0..2
    const unsigned gy0 = by * 32u;
    const unsigned gz0 = bz * 128u;
    const int  P0    = bc * XP;
    const bool lastc = (bc == XC - 1);
    const bool ey    = (by == YT - 1);     // halo row 32 is global y=384
    const bool ez    = (bz == ZT - 1);     // halo col 128 is global z=384
    const int  TMAX  = lastc ? XP + 1 : XP;

    f4v m0, m1, m2, m3;                    // plane x = P0+tt (being loaded)
    f4v p0, p1, p2, p3;                    // plane x-1 (carried from last round)
    f4v h, hp;                             // halo regs (role depends on ty)
    float h2 = 0.f, h2p = 0.f;             // corner halo (ty==2 && tz==0)

    const float* rowp = a + ((unsigned)P0 * (unsigned)PLANE + gy0 * (unsigned)G + gz0);

    for (int tt = 0; tt <= TMAX; ++tt) {
        // ---- [1] issue de-phased global loads for plane x = P0+tt ----
        if (tt <= XP) {
            const float* rp = rowp + 4u * (unsigned)tz;
            m0 = ldg4u(rp + (unsigned)(ty     ) * G);
            m1 = ldg4u(rp + (unsigned)(ty +  8) * G);
            m2 = ldg4u(rp + (unsigned)(ty + 16) * G);
            m3 = ldg4u(rp + (unsigned)(ty + 24) * G);
            if (ty == 0) {                             // y-halo row 32 main
                h = ldg4u(rowp + 32u * G + 4u * (unsigned)tz);
            } else if (ty == 1) {                      // z-halo col, row tz
                h[0] = rowp[(unsigned)tz * G + 128u];
            } else if (ty == 2 && tz == 0) {           // corner halo
                h2 = rowp[32u * G + 128u];
            }
        }

        // ---- [2] compute plane xc = P0+tt-1 from p-regs + LDS ----
        if (tt >= 1) {
            const float (*C)[S] = T[(tt - 1) & 1];
            const bool xd = (tt <= XP);    // x-pair (xc, xc+1) exists

            #pragma unroll
            for (int rr = 0; rr < 4; ++rr) {
                const int r = ty + 8 * rr;
                const f4v v = rr == 0 ? p0 : rr == 1 ? p1 : rr == 2 ? p2 : p3;
                // z-diffs: 3 in-register + chunk boundary via shfl (lane 31
                // patched from the LDS halo column written last round)
                s += fabsf(v[1] - v[0]) + fabsf(v[2] - v[1]) + fabsf(v[3] - v[2]);
                float zb = __shfl_down(v[0], 1);
                if (tz == 31) zb = C[r][128];
                s += fabsf(zb - v[3]);
                // y-diffs: one aligned b128 read of row r+1
                const f4v yn = *(const f4v*)&C[r + 1][4 * tz];
                s += fabsf(yn[0] - v[0]) + fabsf(yn[1] - v[1])
                   + fabsf(yn[2] - v[2]) + fabsf(yn[3] - v[3]);
            }

            if (ey && ty == 0) {           // y=384 row: its own z-diffs
                s += fabsf(hp[1] - hp[0]) + fabsf(hp[2] - hp[1]) + fabsf(hp[3] - hp[2]);
                float zb = __shfl_down(hp[0], 1);
                if (tz == 31) zb = C[32][128];
                s += fabsf(zb - hp[3]);
            }
            if (ez && ty == 1) {           // z=384 col: y-diff (row tz -> tz+1)
                s += fabsf(C[tz + 1][128] - hp[0]);
            }

            if (xd) {                      // x-diffs |plane x - plane xc| in-register
                #pragma unroll
                for (int rr = 0; rr < 4; ++rr) {
                    const f4v v = rr == 0 ? p0 : rr == 1 ? p1 : rr == 2 ? p2 : p3;
                    const f4v w = rr == 0 ? m0 : rr == 1 ? m1 : rr == 2 ? m2 : m3;
                    s += fabsf(w[0] - v[0]) + fabsf(w[1] - v[1])
                       + fabsf(w[2] - v[2]) + fabsf(w[3] - v[3]);
                }
                if (ey && ty == 0)
                    s += fabsf(h[0] - hp[0]) + fabsf(h[1] - hp[1])
                       + fabsf(h[2] - hp[2]) + fabsf(h[3] - hp[3]);
                if (ez && ty == 1)                        s += fabsf(h[0] - hp[0]);
                if (ey && ez && ty == 2 && tz == 0)       s += fabsf(h2 - h2p);
            }
        }

        // ---- [3] write plane x into T[tt&1]; carry regs ----
        // (compute only read T[(tt-1)&1]; one barrier per round suffices)
        if (tt <= XP) {
            float (*B)[S] = T[tt & 1];
            *(f4v*)&B[ty      ][4 * tz] = m0;
            *(f4v*)&B[ty +  8][4 * tz] = m1;
            *(f4v*)&B[ty + 16][4 * tz] = m2;
            *(f4v*)&B[ty + 24][4 * tz] = m3;
            if      (ty == 0)            *(f4v*)&B[32][4 * tz] = h;
            else if (ty == 1)            B[tz][128] = h[0];
            else if (ty == 2 && tz == 0) B[32][128] = h2;
            p0 = m0; p1 = m1; p2 = m2; p3 = m3; hp = h; h2p = h2;
            rowp += PLANE;
        }
        __syncthreads();
    }

    // ---- block reduction ----
    #pragma unroll
    for (int off = 32; off > 0; off >>= 1) s += __shfl_down(s, off, 64);
    __shared__ float ls[TPB / 64];
    const int lane = threadIdx.x & 63;
    const int wid  = threadIdx.x >> 6;
    if (lane == 0) ls[wid] = s;
    __syncthreads();
    if (threadIdx.x == 0) {
        float tsum = 0.f;
        #pragma unroll
        for (int w = 0; w < TPB / 64; ++w) tsum += ls[w];
        ws[blockIdx.x] = tsum;
    }
}

__global__ __launch_bounds__(256) void occ_conn_final(
    const float* __restrict__ ws, float* __restrict__ out)
{
    float s = 0.f;
    for (int i = threadIdx.x; i < NBLK; i += 256) s += ws[i];
    #pragma unroll
    for (int off = 32; off > 0; off >>= 1) s += __shfl_down(s, off, 64);
    __shared__ float ls[4];
    const int lane = threadIdx.x & 63;
    const int wid  = threadIdx.x >> 6;
    if (lane == 0) ls[wid] = s;
    __syncthreads();
    if (threadIdx.x == 0) out[0] = ls[0] + ls[1] + ls[2] + ls[3];
}

extern "C" void kernel_launch(void* const* d_in, const int* in_sizes, int n_in,
                              void* d_out, int out_size, void* d_ws, size_t ws_size,
                              hipStream_t stream)
{
    const float* a   = (const float*)d_in[0];
    float*       out = (float*)d_out;
    float*       ws  = (float*)d_ws;   // NBLK floats; fully overwritten each call

    occ_conn_main<<<NBLK, TPB, 0, stream>>>(a, ws);
    occ_conn_final<<<1, 256, 0, stream>>>(ws, out);
}

// Round 2
// 315.801 us; speedup vs baseline: 1.0084x; 1.0028x over previous
//
#include <hip/hip_runtime.h>

// OccupancyConnectivity on a 385^3 fp32 grid (z innermost, y stride 385,
// x stride 148225). total = sum over 3 forward axes of |a[p+off]-a[p]|.
//
// v3: like v2 (de-phased dwordx4 loads, z/y-diffs in-register + one aligned
// ds_read_b128 per row, single barrier per round) but x-diffs are computed
// one plane LATE: |p - pp| with a second carried register set (plane x-2),
// so the compute phase reads NOTHING from this round's in-flight loads.
// The only vmcnt(0) sits right before the ds_writes at round end => the
// full compute phase hides the ~900-cyc HBM-miss latency (v2 stalled
// mid-compute on the x-diff's |m - p|).
// Input (228 MB) fits in L3, so halo redundancy costs L3 BW only; HBM
// floor = 228.3 MB ~= 34 us.

constexpr int G     = 385;
constexpr int PLANE = G * G;             // 148225

#define TPB   256
#define ZT    3                          // z-tiles of 128 (z in [0,384))
#define YT    12                         // y-tiles of 32 (y in [0,384))
#define XC    16                         // x-chunks of 24 pairs (25 planes)
#define XP    24                         // x-pairs per chunk
#define NBLK  (ZT * YT * XC)             // 576 blocks
#define S     140                        // LDS row stride in floats (mult of 4)

typedef float f4v __attribute__((ext_vector_type(4)));

// misaligned-capable 16B load (address is only 4B-aligned)
static __device__ __forceinline__ f4v ldg4u(const float* __restrict__ p) {
    f4v r;
    __builtin_memcpy(&r, p, sizeof(r));
    return r;
}

__global__ __launch_bounds__(TPB) void occ_conn_main(
    const float* __restrict__ a, float* __restrict__ ws)
{
    __shared__ float T[2][33][S];          // 2 x 33 x 140 x 4B = 36960 B
    float s = 0.f;

    const int tz = threadIdx.x & 31;       // z-chunk lane: z = gz0 + 4*tz..+3
    const int ty = threadIdx.x >> 5;       // row group 0..7 (rows ty+8*rr)

    int t = blockIdx.x;
    const int bc = t % XC;  t /= XC;
    const int by = t % YT;  t /= YT;
    const int bz = t;                      // 0..2
    const unsigned gy0 = by * 32u;
    const unsigned gz0 = bz * 128u;
    const int  P0    = bc * XP;
    const bool lastc = (bc == XC - 1);
    const bool ey    = (by == YT - 1);     // halo row 32 is global y=384
    const bool ez    = (bz == ZT - 1);     // halo col 128 is global z=384

    f4v m0, m1, m2, m3;                    // plane x = P0+tt (in flight)
    f4v p0, p1, p2, p3;                    // plane x-1 (complete)
    f4v q0, q1, q2, q3;                    // plane x-2 (complete)
    f4v h, hp, hq;                         // halo regs (role depends on ty)
    float h2 = 0.f, h2p = 0.f, h2q = 0.f;  // corner halo (ty==2 && tz==0)

    const float* rowp = a + ((unsigned)P0 * (unsigned)PLANE + gy0 * (unsigned)G + gz0);

    // rounds: tt<=XP loads plane P0+tt; compute at tt>=1 does z/y-diffs of
    // plane xc=tt-1 (from p regs + LDS) and at tt>=2 the x-pair (tt-2,tt-1)
    // from (q,p) regs. Final round tt=XP+1: x-pair (XP-1,XP) (+ z/y of the
    // global last plane when lastc).
    for (int tt = 0; tt <= XP + 1; ++tt) {
        // ---- [1] issue de-phased global loads for plane x = P0+tt ----
        if (tt <= XP) {
            const float* rp = rowp + 4u * (unsigned)tz;
            m0 = ldg4u(rp + (unsigned)(ty     ) * G);
            m1 = ldg4u(rp + (unsigned)(ty +  8) * G);
            m2 = ldg4u(rp + (unsigned)(ty + 16) * G);
            m3 = ldg4u(rp + (unsigned)(ty + 24) * G);
            if (ty == 0) {                             // y-halo row 32 main
                h = ldg4u(rowp + 32u * G + 4u * (unsigned)tz);
            } else if (ty == 1) {                      // z-halo col, row tz
                h[0] = rowp[(unsigned)tz * G + 128u];
            } else if (ty == 2 && tz == 0) {           // corner halo
                h2 = rowp[32u * G + 128u];
            }
        }

        // ---- [2] compute: z/y of plane tt-1, x-pair (tt-2, tt-1) ----
        if (tt >= 1) {
            const int xc = tt - 1;
            const float (*C)[S] = T[(tt - 1) & 1];     // plane xc
            const bool zy = (xc < XP) || (lastc && xc == XP);
            const bool xd = (tt >= 2);

            if (zy) {
                #pragma unroll
                for (int rr = 0; rr < 4; ++rr) {
                    const int r = ty + 8 * rr;
                    const f4v v = rr == 0 ? p0 : rr == 1 ? p1 : rr == 2 ? p2 : p3;
                    // z-diffs: 3 in-register + chunk boundary via shfl
                    s += fabsf(v[1] - v[0]) + fabsf(v[2] - v[1]) + fabsf(v[3] - v[2]);
                    float zb = __shfl_down(v[0], 1);
                    if (tz == 31) zb = C[r][128];
                    s += fabsf(zb - v[3]);
                    // y-diffs: one aligned b128 read of row r+1
                    const f4v yn = *(const f4v*)&C[r + 1][4 * tz];
                    s += fabsf(yn[0] - v[0]) + fabsf(yn[1] - v[1])
                       + fabsf(yn[2] - v[2]) + fabsf(yn[3] - v[3]);
                }
                if (ey && ty == 0) {       // y=384 row: its own z-diffs
                    s += fabsf(hp[1] - hp[0]) + fabsf(hp[2] - hp[1]) + fabsf(hp[3] - hp[2]);
                    float zb = __shfl_down(hp[0], 1);
                    if (tz == 31) zb = C[32][128];
                    s += fabsf(zb - hp[3]);
                }
                if (ez && ty == 1) {       // z=384 col: y-diff (row tz -> tz+1)
                    s += fabsf(C[tz + 1][128] - hp[0]);
                }
            }

            if (xd) {                      // x-diffs |plane tt-1 - plane tt-2|
                #pragma unroll
                for (int rr = 0; rr < 4; ++rr) {
                    const f4v v = rr == 0 ? p0 : rr == 1 ? p1 : rr == 2 ? p2 : p3;
                    const f4v w = rr == 0 ? q0 : rr == 1 ? q1 : rr == 2 ? q2 : q3;
                    s += fabsf(w[0] - v[0]) + fabsf(w[1] - v[1])
                       + fabsf(w[2] - v[2]) + fabsf(w[3] - v[3]);
                }
                if (ey && ty == 0)
                    s += fabsf(hp[0] - hq[0]) + fabsf(hp[1] - hq[1])
                       + fabsf(hp[2] - hq[2]) + fabsf(hp[3] - hq[3]);
                if (ez && ty == 1)                        s += fabsf(hp[0] - hq[0]);
                if (ey && ez && ty == 2 && tz == 0)       s += fabsf(h2p - h2q);
            }
        }

        // ---- [3] write plane tt into T[tt&1]; shift carried regs ----
        // (compute read only T[(tt-1)&1] and regs; one barrier per round)
        if (tt <= XP) {
            float (*B)[S] = T[tt & 1];
            *(f4v*)&B[ty      ][4 * tz] = m0;
            *(f4v*)&B[ty +  8][4 * tz] = m1;
            *(f4v*)&B[ty + 16][4 * tz] = m2;
            *(f4v*)&B[ty + 24][4 * tz] = m3;
            if      (ty == 0)            *(f4v*)&B[32][4 * tz] = h;
            else if (ty == 1)            B[tz][128] = h[0];
            else if (ty == 2 && tz == 0) B[32][128] = h2;
            q0 = p0; q1 = p1; q2 = p2; q3 = p3;
            p0 = m0; p1 = m1; p2 = m2; p3 = m3;
            hq = hp; hp = h;  h2q = h2p; h2p = h2;
            rowp += PLANE;
        }
        __syncthreads();
    }

    // ---- block reduction ----
    #pragma unroll
    for (int off = 32; off > 0; off >>= 1) s += __shfl_down(s, off, 64);
    __shared__ float ls[TPB / 64];
    const int lane = threadIdx.x & 63;
    const int wid  = threadIdx.x >> 6;
    if (lane == 0) ls[wid] = s;
    __syncthreads();
    if (threadIdx.x == 0) {
        float tsum = 0.f;
        #pragma unroll
        for (int w = 0; w < TPB / 64; ++w) tsum += ls[w];
        ws[blockIdx.x] = tsum;
    }
}

__global__ __launch_bounds__(256) void occ_conn_final(
    const float* __restrict__ ws, float* __restrict__ out)
{
    float s = 0.f;
    for (int i = threadIdx.x; i < NBLK; i += 256) s += ws[i];
    #pragma unroll
    for (int off = 32; off > 0; off >>= 1) s += __shfl_down(s, off, 64);
    __shared__ float ls[4];
    const int lane = threadIdx.x & 63;
    const int wid  = threadIdx.x >> 6;
    if (lane == 0) ls[wid] = s;
    __syncthreads();
    if (threadIdx.x == 0) out[0] = ls[0] + ls[1] + ls[2] + ls[3];
}

extern "C" void kernel_launch(void* const* d_in, const int* in_sizes, int n_in,
                              void* d_out, int out_size, void* d_ws, size_t ws_size,
                              hipStream_t stream)
{
    const float* a   = (const float*)d_in[0];
    float*       out = (float*)d_out;
    float*       ws  = (float*)d_ws;   // NBLK floats; fully overwritten each call

    occ_conn_main<<<NBLK, TPB, 0, stream>>>(a, ws);
    occ_conn_final<<<1, 256, 0, stream>>>(ws, out);
}

// Round 3
// 315.169 us; speedup vs baseline: 1.0104x; 1.0020x over previous
//
#include <hip/hip_runtime.h>

// OccupancyConnectivity on a 385^3 fp32 grid (z innermost, y stride 385,
// x stride 148225). total = sum over 3 forward axes of |a[p+off]-a[p]|.
//
// v4: 2-deep load pipeline so vmcnt NEVER drains to 0 in the main loop
// (T4 discipline). Round tt: issue loads plane tt -> m; compute plane tt-2
// (z/y from p2-regs + LDS, x-pair (tt-3,tt-2) from q/p2-regs); ds_write
// plane tt-1 (regs n, issued a full round ago => already returned, the
// compiler's waitcnt is vmcnt(~5) not vmcnt(0)); barrier; shift regs.
// Loads stay in flight across every barrier => per-round drain stall
// (~2500-3000 cyc in v3) disappears. Single barrier per round unchanged.
// HBM floor = 228.3 MB ~ 34.7 us; v3 main ran ~43 us.

constexpr int G     = 385;
constexpr int PLANE = G * G;             // 148225

#define TPB   256
#define ZT    3                          // z-tiles of 128 (z in [0,384))
#define YT    12                         // y-tiles of 32 (y in [0,384))
#define XC    16                         // x-chunks of 24 pairs (25 planes)
#define XP    24                         // x-pairs per chunk
#define NBLK  (ZT * YT * XC)             // 576 blocks
#define S     140                        // LDS row stride in floats (mult of 4)

typedef float f4v __attribute__((ext_vector_type(4)));

// misaligned-capable 16B load (address is only 4B-aligned)
static __device__ __forceinline__ f4v ldg4u(const float* __restrict__ p) {
    f4v r;
    __builtin_memcpy(&r, p, sizeof(r));
    return r;
}

__global__ __launch_bounds__(TPB) void occ_conn_main(
    const float* __restrict__ a, float* __restrict__ ws)
{
    __shared__ float T[2][33][S];          // 2 x 33 x 140 x 4B = 36960 B
    float s = 0.f;

    const int tz = threadIdx.x & 31;       // z-chunk lane: z = gz0 + 4*tz..+3
    const int ty = threadIdx.x >> 5;       // row group 0..7 (rows ty+8*rr)

    int t = blockIdx.x;
    const int bc = t % XC;  t /= XC;
    const int by = t % YT;  t /= YT;
    const int bz = t;                      // 0..2
    const unsigned gy0 = by * 32u;
    const unsigned gz0 = bz * 128u;
    const int  P0    = bc * XP;
    const bool lastc = (bc == XC - 1);
    const bool ey    = (by == YT - 1);     // halo row 32 is global y=384
    const bool ez    = (bz == ZT - 1);     // halo col 128 is global z=384

    f4v m0, m1, m2, m3;                    // plane tt   (in flight)
    f4v n0, n1, n2, n3;                    // plane tt-1 (returned; ds_write this round)
    f4v p0, p1, p2, p3;                    // plane tt-2 (compute z/y now)
    f4v q0, q1, q2, q3;                    // plane tt-3 (x-diff partner)
    f4v h, hn, hp, hq;                     // halo regs (role depends on ty)
    float h2 = 0.f, h2n = 0.f, h2p = 0.f, h2q = 0.f;   // corner halo

    const float* rowp = a + ((unsigned)P0 * (unsigned)PLANE + gy0 * (unsigned)G + gz0);

    for (int tt = 0; tt <= XP + 2; ++tt) {
        // ---- [1] issue de-phased global loads for plane tt ----
        if (tt <= XP) {
            const float* rp = rowp + 4u * (unsigned)tz;
            m0 = ldg4u(rp + (unsigned)(ty     ) * G);
            m1 = ldg4u(rp + (unsigned)(ty +  8) * G);
            m2 = ldg4u(rp + (unsigned)(ty + 16) * G);
            m3 = ldg4u(rp + (unsigned)(ty + 24) * G);
            if (ty == 0) {                             // y-halo row 32 main
                h = ldg4u(rowp + 32u * G + 4u * (unsigned)tz);
            } else if (ty == 1) {                      // z-halo col, row tz
                h[0] = rowp[(unsigned)tz * G + 128u];
            } else if (ty == 2 && tz == 0) {           // corner halo
                h2 = rowp[32u * G + 128u];
            }
        }

        // ---- [2] compute: z/y of plane tt-2, x-pair (tt-3, tt-2) ----
        if (tt >= 2) {
            const int xc = tt - 2;
            const float (*C)[S] = T[xc & 1];           // plane xc
            const bool zy = (xc < XP) || (lastc && xc == XP);
            const bool xd = (xc >= 1);

            if (zy) {
                #pragma unroll
                for (int rr = 0; rr < 4; ++rr) {
                    const int r = ty + 8 * rr;
                    const f4v v = rr == 0 ? p0 : rr == 1 ? p1 : rr == 2 ? p2 : p3;
                    // z-diffs: 3 in-register + chunk boundary via shfl
                    s += fabsf(v[1] - v[0]) + fabsf(v[2] - v[1]) + fabsf(v[3] - v[2]);
                    float zb = __shfl_down(v[0], 1);
                    if (tz == 31) zb = C[r][128];
                    s += fabsf(zb - v[3]);
                    // y-diffs: one aligned b128 read of row r+1
                    const f4v yn = *(const f4v*)&C[r + 1][4 * tz];
                    s += fabsf(yn[0] - v[0]) + fabsf(yn[1] - v[1])
                       + fabsf(yn[2] - v[2]) + fabsf(yn[3] - v[3]);
                }
                if (ey && ty == 0) {       // y=384 row: its own z-diffs
                    s += fabsf(hp[1] - hp[0]) + fabsf(hp[2] - hp[1]) + fabsf(hp[3] - hp[2]);
                    float zb = __shfl_down(hp[0], 1);
                    if (tz == 31) zb = C[32][128];
                    s += fabsf(zb - hp[3]);
                }
                if (ez && ty == 1) {       // z=384 col: y-diff (row tz -> tz+1)
                    s += fabsf(C[tz + 1][128] - hp[0]);
                }
            }

            if (xd) {                      // x-diffs |plane xc - plane xc-1|
                #pragma unroll
                for (int rr = 0; rr < 4; ++rr) {
                    const f4v v = rr == 0 ? p0 : rr == 1 ? p1 : rr == 2 ? p2 : p3;
                    const f4v w = rr == 0 ? q0 : rr == 1 ? q1 : rr == 2 ? q2 : q3;
                    s += fabsf(w[0] - v[0]) + fabsf(w[1] - v[1])
                       + fabsf(w[2] - v[2]) + fabsf(w[3] - v[3]);
                }
                if (ey && ty == 0)
                    s += fabsf(hp[0] - hq[0]) + fabsf(hp[1] - hq[1])
                       + fabsf(hp[2] - hq[2]) + fabsf(hp[3] - hq[3]);
                if (ez && ty == 1)                        s += fabsf(hp[0] - hq[0]);
                if (ey && ez && ty == 2 && tz == 0)       s += fabsf(h2p - h2q);
            }
        }

        // ---- [3] write plane tt-1 (regs n, already returned) into LDS ----
        if (tt >= 1 && tt <= XP + 1) {
            float (*B)[S] = T[(tt - 1) & 1];
            *(f4v*)&B[ty      ][4 * tz] = n0;
            *(f4v*)&B[ty +  8][4 * tz] = n1;
            *(f4v*)&B[ty + 16][4 * tz] = n2;
            *(f4v*)&B[ty + 24][4 * tz] = n3;
            if      (ty == 0)            *(f4v*)&B[32][4 * tz] = hn;
            else if (ty == 1)            B[tz][128] = hn[0];
            else if (ty == 2 && tz == 0) B[32][128] = h2n;
        }

        // ---- [4] shift carried regs ----
        if (tt <= XP + 1) {
            q0 = p0; q1 = p1; q2 = p2; q3 = p3;
            p0 = n0; p1 = n1; p2 = n2; p3 = n3;
            hq = hp; hp = hn; h2q = h2p; h2p = h2n;
        }
        if (tt <= XP) {
            n0 = m0; n1 = m1; n2 = m2; n3 = m3;
            hn = h;  h2n = h2;
            rowp += PLANE;
        }
        __syncthreads();
    }

    // ---- block reduction ----
    #pragma unroll
    for (int off = 32; off > 0; off >>= 1) s += __shfl_down(s, off, 64);
    __shared__ float ls[TPB / 64];
    const int lane = threadIdx.x & 63;
    const int wid  = threadIdx.x >> 6;
    if (lane == 0) ls[wid] = s;
    __syncthreads();
    if (threadIdx.x == 0) {
        float tsum = 0.f;
        #pragma unroll
        for (int w = 0; w < TPB / 64; ++w) tsum += ls[w];
        ws[blockIdx.x] = tsum;
    }
}

__global__ __launch_bounds__(256) void occ_conn_final(
    const float* __restrict__ ws, float* __restrict__ out)
{
    float s = 0.f;
    for (int i = threadIdx.x; i < NBLK; i += 256) s += ws[i];
    #pragma unroll
    for (int off = 32; off > 0; off >>= 1) s += __shfl_down(s, off, 64);
    __shared__ float ls[4];
    const int lane = threadIdx.x & 63;
    const int wid  = threadIdx.x >> 6;
    if (lane == 0) ls[wid] = s;
    __syncthreads();
    if (threadIdx.x == 0) out[0] = ls[0] + ls[1] + ls[2] + ls[3];
}

extern "C" void kernel_launch(void* const* d_in, const int* in_sizes, int n_in,
                              void* d_out, int out_size, void* d_ws, size_t ws_size,
                              hipStream_t stream)
{
    const float* a   = (const float*)d_in[0];
    float*       out = (float*)d_out;
    float*       ws  = (float*)d_ws;   // NBLK floats; fully overwritten each call

    occ_conn_main<<<NBLK, TPB, 0, stream>>>(a, ws);
    occ_conn_final<<<1, 256, 0, stream>>>(ws, out);
}